// Round 1
// baseline (113.911 us; speedup 1.0000x reference)
//
#include <hip/hip_runtime.h>
#include <hip/hip_bf16.h>

// Problem constants (fixed by the reference file)
#define NN    4096   // nodes
#define EE    4096   // edges
#define DM    256    // model dim
#define EDIM  64     // edge feature dim
#define HH    8      // heads
#define DHd   32     // head dim
#define DEGc  8
#define CARDc 8
#define LL    64     // deg*card

typedef short  s16x8 __attribute__((ext_vector_type(8)));
typedef unsigned short u16x8 __attribute__((ext_vector_type(8)));
typedef float  f32x4 __attribute__((ext_vector_type(4)));

__device__ __forceinline__ float b2f(unsigned short u) {
  return __uint_as_float(((unsigned int)u) << 16);
}
__device__ __forceinline__ unsigned short f2b_bits(float f) {
  unsigned int u = __float_as_uint(f);
  u = (u + 0x7FFFu + ((u >> 16) & 1u)) >> 16;   // RNE
  return (unsigned short)u;
}

// ---------------- f32 -> bf16 convert (vectorized) ----------------
__global__ __launch_bounds__(256) void f2b_vec(const float* __restrict__ in,
                                               unsigned short* __restrict__ out,
                                               int n4) {
  int i = blockIdx.x * 256 + threadIdx.x;
  if (i >= n4) return;
  float4 v = ((const float4*)in)[i];
  ushort4 o;
  o.x = f2b_bits(v.x); o.y = f2b_bits(v.y); o.z = f2b_bits(v.z); o.w = f2b_bits(v.w);
  ((ushort4*)out)[i] = o;
}

// ---------------- adjacency build: one pass over incidence ----------------
__global__ __launch_bounds__(256) void build_adj(const float* __restrict__ inc,
                                                 int* __restrict__ cnt_e,
                                                 int* __restrict__ cnt_n,
                                                 int* __restrict__ noe,   // node_of_edge [E][8]
                                                 int* __restrict__ eon) { // edge_of_node [N][8]
  int t = blockIdx.x * 256 + threadIdx.x;       // < E*N/4
  float4 v = ((const float4*)inc)[t];
  int flat = t * 4;
  int e  = flat >> 12;        // N = 4096
  int u0 = flat & 4095;
  float vals[4] = {v.x, v.y, v.z, v.w};
#pragma unroll
  for (int j = 0; j < 4; ++j) {
    if (vals[j] != 0.0f) {
      int u  = u0 + j;
      int pe = atomicAdd(&cnt_e[e], 1);
      noe[e * 8 + pe] = u;
      int pn = atomicAdd(&cnt_n[u], 1);
      eon[u * 8 + pn] = e;
    }
  }
}

// ---------------- MFMA GEMM, C[i][j] = sum_k A[i][k]*B[j][k] ----------------
// A: M x K bf16 row-major; B: N x K bf16 row-major (i.e. B^T in math terms).
// 64x64 tile per block, 4 waves, 16x16x32 bf16 MFMA. Epilogue by mode.
#define MODE_PLAIN 0
#define MODE_PROJ  1
#define MODE_OUT   2

__global__ __launch_bounds__(256) void gemm_bt(
    const unsigned short* __restrict__ A, const unsigned short* __restrict__ B,
    int M, int N, int K, int mode,
    float* __restrict__ out_f, unsigned short* __restrict__ out_b,
    unsigned short* __restrict__ out_b2, const float* __restrict__ bias) {
  __shared__ short As[64 * 40] __attribute__((aligned(16)));  // pad 32->40 (80B rows, 16B-aligned)
  __shared__ short Bs[64 * 40] __attribute__((aligned(16)));
  const int tid  = threadIdx.x;
  const int wid  = tid >> 6, lane = tid & 63;
  const int i0   = blockIdx.x * 64, j0 = blockIdx.y * 64;
  const int wr   = (wid >> 1) * 32, wc = (wid & 1) * 32;
  const int srow = tid >> 2, schunk = (tid & 3) * 8;
  const int fr   = lane & 15, fk = (lane >> 4) * 8;

  f32x4 acc[2][2];
#pragma unroll
  for (int a = 0; a < 2; ++a)
#pragma unroll
    for (int b = 0; b < 2; ++b) acc[a][b] = (f32x4){0.f, 0.f, 0.f, 0.f};

  for (int kk = 0; kk < K; kk += 32) {
    *(s16x8*)&As[srow * 40 + schunk] = *(const s16x8*)&A[(size_t)(i0 + srow) * K + kk + schunk];
    *(s16x8*)&Bs[srow * 40 + schunk] = *(const s16x8*)&B[(size_t)(j0 + srow) * K + kk + schunk];
    __syncthreads();
    s16x8 af0 = *(const s16x8*)&As[(wr + fr) * 40 + fk];
    s16x8 af1 = *(const s16x8*)&As[(wr + 16 + fr) * 40 + fk];
    s16x8 bf0 = *(const s16x8*)&Bs[(wc + fr) * 40 + fk];
    s16x8 bf1 = *(const s16x8*)&Bs[(wc + 16 + fr) * 40 + fk];
    acc[0][0] = __builtin_amdgcn_mfma_f32_16x16x32_bf16(af0, bf0, acc[0][0], 0, 0, 0);
    acc[0][1] = __builtin_amdgcn_mfma_f32_16x16x32_bf16(af0, bf1, acc[0][1], 0, 0, 0);
    acc[1][0] = __builtin_amdgcn_mfma_f32_16x16x32_bf16(af1, bf0, acc[1][0], 0, 0, 0);
    acc[1][1] = __builtin_amdgcn_mfma_f32_16x16x32_bf16(af1, bf1, acc[1][1], 0, 0, 0);
    __syncthreads();
  }

  const int ecol = lane & 15, erow0 = (lane >> 4) * 4;
#pragma unroll
  for (int mi = 0; mi < 2; ++mi)
#pragma unroll
    for (int ni = 0; ni < 2; ++ni) {
#pragma unroll
      for (int v = 0; v < 4; ++v) {
        int i = i0 + wr + mi * 16 + erow0 + v;
        int j = j0 + wc + ni * 16 + ecol;
        float val = acc[mi][ni][v];
        if (mode == MODE_PLAIN) {
          out_b[(size_t)i * N + j] = f2b_bits(val);
        } else if (mode == MODE_PROJ) {
          if (j < 256)      out_f[(size_t)i * 256 + j]          = val + bias[j];
          else if (j < 512) out_b[(size_t)i * 256 + (j - 256)]  = f2b_bits(val);
          else              out_b2[(size_t)i * 256 + (j - 512)] = f2b_bits(val + bias[j]);
        } else { // MODE_OUT: bias + relu, f32 out
          float r = val + bias[j];
          out_f[(size_t)i * N + j] = r > 0.f ? r : 0.f;
        }
      }
    }
}

// ---------------- node-centric attention ----------------
// 1 block per node, 512 threads = 8 waves = 8 heads; L=64 pairs = 64 lanes.
__global__ __launch_bounds__(512) void attn_kernel(
    const float* __restrict__ q, const unsigned short* __restrict__ Kn,
    const unsigned short* __restrict__ Vn, const unsigned short* __restrict__ Ke,
    const int* __restrict__ eon, const int* __restrict__ noe,
    unsigned short* __restrict__ ctx) {
  const int n = blockIdx.x;
  __shared__ int   e_s[8];
  __shared__ int   u_s[64];
  __shared__ float q_s[256];
  __shared__ float attn_s[8][64];
  const int tid = threadIdx.x;
  if (tid < 8) e_s[tid] = eon[n * 8 + tid];
  if (tid >= 256) q_s[tid - 256] = q[(size_t)n * 256 + (tid - 256)];
  __syncthreads();
  if (tid < 64) u_s[tid] = noe[e_s[tid >> 3] * 8 + (tid & 7)];
  __syncthreads();

  const int h = tid >> 6, l = tid & 63;
  const int u = u_s[l], e = e_s[l >> 3];
  const u16x8* kp = (const u16x8*)(Kn + ((size_t)u * 256 + h * 32));
  const u16x8* ep = (const u16x8*)(Ke + ((size_t)e * 256 + h * 32));
  float s = 0.f;
#pragma unroll
  for (int c = 0; c < 4; ++c) {
    u16x8 kv = kp[c];
    u16x8 ev = ep[c];
#pragma unroll
    for (int j = 0; j < 8; ++j)
      s += q_s[h * 32 + c * 8 + j] * (b2f(kv[j]) + b2f(ev[j]));
  }
  s *= 0.17677669529663687f;  // 1/sqrt(32)

  float m = s;
#pragma unroll
  for (int off = 32; off >= 1; off >>= 1) m = fmaxf(m, __shfl_xor(m, off));
  float p = __expf(s - m);
  float sum = p;
#pragma unroll
  for (int off = 32; off >= 1; off >>= 1) sum += __shfl_xor(sum, off);
  attn_s[h][l] = p / sum;
  __syncthreads();

  const int d = l & 31, half = l >> 5;
  float acc = 0.f;
#pragma unroll
  for (int t2 = 0; t2 < 32; ++t2) {
    int ll = half * 32 + t2;
    acc += attn_s[h][ll] * b2f(Vn[(size_t)u_s[ll] * 256 + h * 32 + d]);
  }
  acc += __shfl_xor(acc, 32);
  if (half == 0) ctx[(size_t)n * 256 + h * 32 + d] = f2b_bits(acc);
}

// ---------------- workspace layout (bytes) ----------------
#define OFF_Q      ((size_t)0)          // 4096*256 f32   = 4 MB
#define OFF_KN     ((size_t)4194304)    // 4096*256 bf16  = 2 MB
#define OFF_VN     ((size_t)6291456)
#define OFF_KE     ((size_t)8388608)
#define OFF_CTX    ((size_t)10485760)
#define OFF_XBF    ((size_t)12582912)   // 4096*256 bf16
#define OFF_EABF   ((size_t)14680064)   // 4096*64 bf16
#define OFF_WOUTBF ((size_t)15204352)   // 256*256 bf16
#define OFF_IPWBF  ((size_t)15335424)   // 768*256 bf16
#define OFF_WLINBF ((size_t)15728640)   // 256*256 bf16
#define OFF_WEDGBF ((size_t)15859712)   // 64*256 bf16
#define OFF_F      ((size_t)15892480)   // 768*256 bf16
#define OFF_G      ((size_t)16285696)   // 256*64 bf16
#define OFF_CNTE   ((size_t)16318464)   // 4096 i32
#define OFF_CNTN   ((size_t)16334848)   // 4096 i32
#define OFF_NOE    ((size_t)16351232)   // 4096*8 i32
#define OFF_EON    ((size_t)16482304)   // 4096*8 i32

extern "C" void kernel_launch(void* const* d_in, const int* in_sizes, int n_in,
                              void* d_out, int out_size, void* d_ws, size_t ws_size,
                              hipStream_t stream) {
  const float* x     = (const float*)d_in[0];   // 4096x256
  const float* inc   = (const float*)d_in[1];   // 4096x4096
  const float* ea    = (const float*)d_in[2];   // 4096x64
  const float* wlin  = (const float*)d_in[3];   // 256x256
  const float* wedge = (const float*)d_in[4];   // 64x256
  const float* ipw   = (const float*)d_in[5];   // 768x256
  const float* ipb   = (const float*)d_in[6];   // 768
  const float* wout  = (const float*)d_in[7];   // 256x256
  const float* outb  = (const float*)d_in[8];   // 256

  char* ws = (char*)d_ws;
  float*          q       = (float*)(ws + OFF_Q);
  unsigned short* Kn      = (unsigned short*)(ws + OFF_KN);
  unsigned short* Vn      = (unsigned short*)(ws + OFF_VN);
  unsigned short* Ke      = (unsigned short*)(ws + OFF_KE);
  unsigned short* ctx     = (unsigned short*)(ws + OFF_CTX);
  unsigned short* x_bf    = (unsigned short*)(ws + OFF_XBF);
  unsigned short* ea_bf   = (unsigned short*)(ws + OFF_EABF);
  unsigned short* wout_bf = (unsigned short*)(ws + OFF_WOUTBF);
  unsigned short* ipw_bf  = (unsigned short*)(ws + OFF_IPWBF);
  unsigned short* wlin_bf = (unsigned short*)(ws + OFF_WLINBF);
  unsigned short* wedg_bf = (unsigned short*)(ws + OFF_WEDGBF);
  unsigned short* F       = (unsigned short*)(ws + OFF_F);
  unsigned short* G       = (unsigned short*)(ws + OFF_G);
  int*            cnt_e   = (int*)(ws + OFF_CNTE);
  int*            cnt_n   = (int*)(ws + OFF_CNTN);
  int*            noe     = (int*)(ws + OFF_NOE);
  int*            eon     = (int*)(ws + OFF_EON);

  // converts (f32 -> bf16)
  f2b_vec<<<1024, 256, 0, stream>>>(x, x_bf, 262144);
  f2b_vec<<<256, 256, 0, stream>>>(ea, ea_bf, 65536);
  f2b_vec<<<64, 256, 0, stream>>>(wout, wout_bf, 16384);
  f2b_vec<<<192, 256, 0, stream>>>(ipw, ipw_bf, 49152);
  f2b_vec<<<64, 256, 0, stream>>>(wlin, wlin_bf, 16384);
  f2b_vec<<<16, 256, 0, stream>>>(wedge, wedg_bf, 4096);

  // adjacency
  hipMemsetAsync(ws + OFF_CNTE, 0, 32768, stream);
  build_adj<<<16384, 256, 0, stream>>>(inc, cnt_e, cnt_n, noe, eon);

  // weight fusion: F = in_proj_w @ W_lin^T  (768x256), G = Wk @ W_edge^T (256x64)
  gemm_bt<<<dim3(12, 4), 256, 0, stream>>>(ipw_bf, wlin_bf, 768, 256, 256,
                                           MODE_PLAIN, nullptr, F, nullptr, nullptr);
  gemm_bt<<<dim3(4, 1), 256, 0, stream>>>(ipw_bf + 256 * 256, wedg_bf, 256, 64, 256,
                                          MODE_PLAIN, nullptr, G, nullptr, nullptr);

  // projections: [q | Kn | Vn] = x @ F^T(cols), Ke = edge_attr @ G^T
  gemm_bt<<<dim3(64, 12), 256, 0, stream>>>(x_bf, F, 4096, 768, 256,
                                            MODE_PROJ, q, Kn, Vn, ipb);
  gemm_bt<<<dim3(64, 4), 256, 0, stream>>>(ea_bf, G, 4096, 256, 64,
                                           MODE_PLAIN, nullptr, Ke, nullptr, nullptr);

  // attention
  attn_kernel<<<4096, 512, 0, stream>>>(q, Kn, Vn, Ke, eon, noe, ctx);

  // output projection + bias + relu -> d_out (f32)
  gemm_bt<<<dim3(64, 4), 256, 0, stream>>>(ctx, wout_bf, 4096, 256, 256,
                                           MODE_OUT, (float*)d_out, nullptr, nullptr, outb);
}

// Round 2
// 88.672 us; speedup vs baseline: 1.2846x; 1.2846x over previous
//
#include <hip/hip_runtime.h>
#include <hip/hip_bf16.h>

// Problem constants (fixed by the reference file)
#define NN    4096
#define EE    4096
#define DM    256
#define EDIM  64
#define HH    8
#define DHd   32
#define LL    64

typedef short  s16x8 __attribute__((ext_vector_type(8)));
typedef unsigned short u16x8 __attribute__((ext_vector_type(8)));
typedef float  f32x4 __attribute__((ext_vector_type(4)));

__device__ __forceinline__ float b2f(unsigned short u) {
  return __uint_as_float(((unsigned int)u) << 16);
}
__device__ __forceinline__ unsigned short f2b_bits(float f) {
  unsigned int u = __float_as_uint(f);
  u = (u + 0x7FFFu + ((u >> 16) & 1u)) >> 16;   // RNE
  return (unsigned short)u;
}

// ---------------- fused f32->bf16 converts + counter zeroing (1 dispatch) ----------------
// ranges (float4 units): x 262144 | ea 65536 | ipw 49152 | wlin 16384 | wedge 4096 | wout 16384
__global__ __launch_bounds__(256) void f2b_all(
    const float* __restrict__ x, const float* __restrict__ ea,
    const float* __restrict__ ipw, const float* __restrict__ wlin,
    const float* __restrict__ wedge, const float* __restrict__ wout,
    unsigned short* __restrict__ xb, unsigned short* __restrict__ eab,
    unsigned short* __restrict__ ipwb, unsigned short* __restrict__ wlinb,
    unsigned short* __restrict__ wedgeb, unsigned short* __restrict__ woutb,
    int* __restrict__ cnt) {
  int i = blockIdx.x * 256 + threadIdx.x;
  if (i < 8192) cnt[i] = 0;                      // zero cnt_e + cnt_n (contiguous)
  const float* src; unsigned short* dst; int j = i;
  if (j < 262144)       { src = x;     dst = xb; }
  else { j -= 262144;
  if (j < 65536)        { src = ea;    dst = eab; }
  else { j -= 65536;
  if (j < 49152)        { src = ipw;   dst = ipwb; }
  else { j -= 49152;
  if (j < 16384)        { src = wlin;  dst = wlinb; }
  else { j -= 16384;
  if (j < 4096)         { src = wedge; dst = wedgeb; }
  else { j -= 4096;
  if (j >= 16384) return;
                          src = wout;  dst = woutb; }}}}}
  float4 v = ((const float4*)src)[j];
  ushort4 o;
  o.x = f2b_bits(v.x); o.y = f2b_bits(v.y); o.z = f2b_bits(v.z); o.w = f2b_bits(v.w);
  ((ushort4*)dst)[j] = o;
}

// ---------------- adjacency build: one pass over incidence ----------------
__global__ __launch_bounds__(256) void build_adj(const float* __restrict__ inc,
                                                 int* __restrict__ cnt_e,
                                                 int* __restrict__ cnt_n,
                                                 int* __restrict__ noe,
                                                 int* __restrict__ eon) {
  int t = blockIdx.x * 256 + threadIdx.x;
  float4 v = ((const float4*)inc)[t];
  int flat = t * 4;
  int e  = flat >> 12;
  int u0 = flat & 4095;
  float vals[4] = {v.x, v.y, v.z, v.w};
#pragma unroll
  for (int j = 0; j < 4; ++j) {
    if (vals[j] != 0.0f) {
      int u  = u0 + j;
      int pe = atomicAdd(&cnt_e[e], 1);
      noe[e * 8 + pe] = u;
      int pn = atomicAdd(&cnt_n[u], 1);
      eon[u * 8 + pn] = e;
    }
  }
}

// ---------------- MFMA GEMM, C[i][j] = sum_k A[i][k]*B[j][k] ----------------
#define MODE_PLAIN 0
#define MODE_PROJ  1
#define MODE_OUT   2

__global__ __launch_bounds__(256) void gemm_bt(
    const unsigned short* __restrict__ A, const unsigned short* __restrict__ B,
    int M, int N, int K, int mode,
    float* __restrict__ out_f, unsigned short* __restrict__ out_b,
    unsigned short* __restrict__ out_b2, const float* __restrict__ bias) {
  __shared__ short As[64 * 40] __attribute__((aligned(16)));
  __shared__ short Bs[64 * 40] __attribute__((aligned(16)));
  const int tid  = threadIdx.x;
  const int wid  = tid >> 6, lane = tid & 63;
  const int i0   = blockIdx.x * 64, j0 = blockIdx.y * 64;
  const int wr   = (wid >> 1) * 32, wc = (wid & 1) * 32;
  const int srow = tid >> 2, schunk = (tid & 3) * 8;
  const int fr   = lane & 15, fk = (lane >> 4) * 8;

  f32x4 acc[2][2];
#pragma unroll
  for (int a = 0; a < 2; ++a)
#pragma unroll
    for (int b = 0; b < 2; ++b) acc[a][b] = (f32x4){0.f, 0.f, 0.f, 0.f};

  for (int kk = 0; kk < K; kk += 32) {
    *(s16x8*)&As[srow * 40 + schunk] = *(const s16x8*)&A[(size_t)(i0 + srow) * K + kk + schunk];
    *(s16x8*)&Bs[srow * 40 + schunk] = *(const s16x8*)&B[(size_t)(j0 + srow) * K + kk + schunk];
    __syncthreads();
    s16x8 af0 = *(const s16x8*)&As[(wr + fr) * 40 + fk];
    s16x8 af1 = *(const s16x8*)&As[(wr + 16 + fr) * 40 + fk];
    s16x8 bf0 = *(const s16x8*)&Bs[(wc + fr) * 40 + fk];
    s16x8 bf1 = *(const s16x8*)&Bs[(wc + 16 + fr) * 40 + fk];
    acc[0][0] = __builtin_amdgcn_mfma_f32_16x16x32_bf16(af0, bf0, acc[0][0], 0, 0, 0);
    acc[0][1] = __builtin_amdgcn_mfma_f32_16x16x32_bf16(af0, bf1, acc[0][1], 0, 0, 0);
    acc[1][0] = __builtin_amdgcn_mfma_f32_16x16x32_bf16(af1, bf0, acc[1][0], 0, 0, 0);
    acc[1][1] = __builtin_amdgcn_mfma_f32_16x16x32_bf16(af1, bf1, acc[1][1], 0, 0, 0);
    __syncthreads();
  }

  const int ecol = lane & 15, erow0 = (lane >> 4) * 4;
#pragma unroll
  for (int mi = 0; mi < 2; ++mi)
#pragma unroll
    for (int ni = 0; ni < 2; ++ni) {
#pragma unroll
      for (int v = 0; v < 4; ++v) {
        int i = i0 + wr + mi * 16 + erow0 + v;
        int j = j0 + wc + ni * 16 + ecol;
        float val = acc[mi][ni][v];
        if (mode == MODE_PLAIN) {
          out_b[(size_t)i * N + j] = f2b_bits(val);
        } else if (mode == MODE_PROJ) {
          if (j < 256)      out_f[(size_t)i * 256 + j]          = val + bias[j];
          else if (j < 512) out_b[(size_t)i * 256 + (j - 256)]  = f2b_bits(val);
          else              out_b2[(size_t)i * 256 + (j - 512)] = f2b_bits(val + bias[j]);
        } else {
          float r = val + bias[j];
          out_f[(size_t)i * N + j] = r > 0.f ? r : 0.f;
        }
      }
    }
}

// ---------------- fused weight GEMMs: F = ipw@wlin^T (768x256), G = Wk@wedge^T (256x64) ----------------
__global__ __launch_bounds__(256) void fuse_w(
    const unsigned short* __restrict__ ipw, const unsigned short* __restrict__ wlin,
    const unsigned short* __restrict__ wedge,
    unsigned short* __restrict__ F, unsigned short* __restrict__ G) {
  const int gpart = (blockIdx.y == 4);
  if (gpart && blockIdx.x >= 4) return;
  const unsigned short* A = gpart ? (ipw + (size_t)(256 + blockIdx.x * 64) * 256)
                                  : (ipw + (size_t)blockIdx.x * 64 * 256);
  const unsigned short* B = gpart ? wedge : wlin;
  unsigned short* outp = gpart ? G : F;
  const int j0 = gpart ? 0 : blockIdx.y * 64;
  const int outN = gpart ? 64 : 256;
  const int i0 = blockIdx.x * 64;

  __shared__ short As[64 * 40] __attribute__((aligned(16)));
  __shared__ short Bs[64 * 40] __attribute__((aligned(16)));
  const int tid  = threadIdx.x;
  const int wid  = tid >> 6, lane = tid & 63;
  const int wr   = (wid >> 1) * 32, wc = (wid & 1) * 32;
  const int srow = tid >> 2, schunk = (tid & 3) * 8;
  const int fr   = lane & 15, fk = (lane >> 4) * 8;

  f32x4 acc[2][2];
#pragma unroll
  for (int a = 0; a < 2; ++a)
#pragma unroll
    for (int b = 0; b < 2; ++b) acc[a][b] = (f32x4){0.f, 0.f, 0.f, 0.f};

  for (int kk = 0; kk < 256; kk += 32) {
    *(s16x8*)&As[srow * 40 + schunk] = *(const s16x8*)&A[(size_t)srow * 256 + kk + schunk];
    *(s16x8*)&Bs[srow * 40 + schunk] = *(const s16x8*)&B[(size_t)(j0 + srow) * 256 + kk + schunk];
    __syncthreads();
    s16x8 af0 = *(const s16x8*)&As[(wr + fr) * 40 + fk];
    s16x8 af1 = *(const s16x8*)&As[(wr + 16 + fr) * 40 + fk];
    s16x8 bf0 = *(const s16x8*)&Bs[(wc + fr) * 40 + fk];
    s16x8 bf1 = *(const s16x8*)&Bs[(wc + 16 + fr) * 40 + fk];
    acc[0][0] = __builtin_amdgcn_mfma_f32_16x16x32_bf16(af0, bf0, acc[0][0], 0, 0, 0);
    acc[0][1] = __builtin_amdgcn_mfma_f32_16x16x32_bf16(af0, bf1, acc[0][1], 0, 0, 0);
    acc[1][0] = __builtin_amdgcn_mfma_f32_16x16x32_bf16(af1, bf0, acc[1][0], 0, 0, 0);
    acc[1][1] = __builtin_amdgcn_mfma_f32_16x16x32_bf16(af1, bf1, acc[1][1], 0, 0, 0);
    __syncthreads();
  }

  const int ecol = lane & 15, erow0 = (lane >> 4) * 4;
#pragma unroll
  for (int mi = 0; mi < 2; ++mi)
#pragma unroll
    for (int ni = 0; ni < 2; ++ni)
#pragma unroll
      for (int v = 0; v < 4; ++v) {
        int i = i0 + wr + mi * 16 + erow0 + v;
        int j = j0 + wc + ni * 16 + ecol;
        if (j < outN) outp[(size_t)i * outN + j] = f2b_bits(acc[mi][ni][v]);
      }
}

// ---------------- node-centric attention (qKe dedup + T14 async-staged V in LDS) ----------------
__global__ __launch_bounds__(512) void attn_kernel(
    const float* __restrict__ q, const unsigned short* __restrict__ Kn,
    const unsigned short* __restrict__ Vn, const unsigned short* __restrict__ Ke,
    const int* __restrict__ eon, const int* __restrict__ noe,
    unsigned short* __restrict__ ctx) {
  const int n = blockIdx.x;
  __shared__ int   e_s[8];
  __shared__ int   u_s[64];
  __shared__ float q_s[256];
  __shared__ float qke_s[64];                         // [h*8+e]
  __shared__ float attn_s[8][64];
  __shared__ unsigned short Vg[64 * 256] __attribute__((aligned(16)));  // linear, no pad
  const int tid = threadIdx.x;
  if (tid < 8) e_s[tid] = eon[n * 8 + tid];
  if (tid >= 256) q_s[tid - 256] = q[(size_t)n * 256 + (tid - 256)];
  __syncthreads();
  if (tid < 64) {
    u_s[tid] = noe[e_s[tid >> 3] * 8 + (tid & 7)];
  } else if (tid < 128) {
    // qke[h][e] = q[h slice] . Ke[e][h slice]   (dedups 8x-duplicated Ke loads)
    const int h = (tid - 64) >> 3, e = tid & 7;
    const u16x8* ep = (const u16x8*)(Ke + (size_t)e_s[e] * 256 + h * 32);
    float s = 0.f;
#pragma unroll
    for (int c = 0; c < 4; ++c) {
      u16x8 ev = ep[c];
#pragma unroll
      for (int j = 0; j < 8; ++j) s += q_s[h * 32 + c * 8 + j] * b2f(ev[j]);
    }
    qke_s[(h << 3) | e] = s;
  }
  __syncthreads();

  // ---- issue V-row gather loads early (latency hides under score phase) ----
  u16x8 vstage[4];
  int vrow[4];
#pragma unroll
  for (int i = 0; i < 4; ++i) {
    int chunk = i * 512 + tid;
    vrow[i] = chunk >> 5;
    int col = (chunk & 31) * 8;
    vstage[i] = *(const u16x8*)(Vn + (size_t)u_s[vrow[i]] * 256 + col);
  }

  // ---- scores ----
  const int h = tid >> 6, l = tid & 63;
  const int u = u_s[l];
  const u16x8* kp = (const u16x8*)(Kn + ((size_t)u * 256 + h * 32));
  float s = 0.f;
#pragma unroll
  for (int c = 0; c < 4; ++c) {
    u16x8 kv = kp[c];
#pragma unroll
    for (int j = 0; j < 8; ++j) s += q_s[h * 32 + c * 8 + j] * b2f(kv[j]);
  }
  s = (s + qke_s[(h << 3) | (l >> 3)]) * 0.17677669529663687f;  // 1/sqrt(32)

  float m = s;
#pragma unroll
  for (int off = 32; off >= 1; off >>= 1) m = fmaxf(m, __shfl_xor(m, off));
  float p = __expf(s - m);
  float sum = p;
#pragma unroll
  for (int off = 32; off >= 1; off >>= 1) sum += __shfl_xor(sum, off);
  attn_s[h][l] = p / sum;

  // ---- write staged V rows to LDS (vmcnt waits land here, after score phase) ----
#pragma unroll
  for (int i = 0; i < 4; ++i) {
    int chunk = i * 512 + tid;
    *(u16x8*)&Vg[(size_t)chunk * 8] = vstage[i];
  }
  __syncthreads();

  // ---- PV from LDS: thread (h, l) -> d = l&31, halves split the 64 pairs ----
  const int d = l & 31, half = l >> 5;
  const unsigned short* vp = &Vg[(size_t)(half * 32) * 256 + h * 32 + d];
  const float* ap = &attn_s[h][half * 32];
  float acc = 0.f;
#pragma unroll
  for (int t2 = 0; t2 < 32; ++t2)
    acc += ap[t2] * b2f(vp[t2 * 256]);
  acc += __shfl_xor(acc, 32);
  if (half == 0) ctx[(size_t)n * 256 + h * 32 + d] = f2b_bits(acc);
}

// ---------------- workspace layout (bytes) ----------------
#define OFF_Q      ((size_t)0)
#define OFF_KN     ((size_t)4194304)
#define OFF_VN     ((size_t)6291456)
#define OFF_KE     ((size_t)8388608)
#define OFF_CTX    ((size_t)10485760)
#define OFF_XBF    ((size_t)12582912)
#define OFF_EABF   ((size_t)14680064)
#define OFF_WOUTBF ((size_t)15204352)
#define OFF_IPWBF  ((size_t)15335424)
#define OFF_WLINBF ((size_t)15728640)
#define OFF_WEDGBF ((size_t)15859712)
#define OFF_F      ((size_t)15892480)
#define OFF_G      ((size_t)16285696)
#define OFF_CNTE   ((size_t)16318464)
#define OFF_CNTN   ((size_t)16334848)
#define OFF_NOE    ((size_t)16351232)
#define OFF_EON    ((size_t)16482304)

extern "C" void kernel_launch(void* const* d_in, const int* in_sizes, int n_in,
                              void* d_out, int out_size, void* d_ws, size_t ws_size,
                              hipStream_t stream) {
  const float* x     = (const float*)d_in[0];
  const float* inc   = (const float*)d_in[1];
  const float* ea    = (const float*)d_in[2];
  const float* wlin  = (const float*)d_in[3];
  const float* wedge = (const float*)d_in[4];
  const float* ipw   = (const float*)d_in[5];
  const float* ipb   = (const float*)d_in[6];
  const float* wout  = (const float*)d_in[7];
  const float* outb  = (const float*)d_in[8];

  char* ws = (char*)d_ws;
  float*          q       = (float*)(ws + OFF_Q);
  unsigned short* Kn      = (unsigned short*)(ws + OFF_KN);
  unsigned short* Vn      = (unsigned short*)(ws + OFF_VN);
  unsigned short* Ke      = (unsigned short*)(ws + OFF_KE);
  unsigned short* ctx     = (unsigned short*)(ws + OFF_CTX);
  unsigned short* x_bf    = (unsigned short*)(ws + OFF_XBF);
  unsigned short* ea_bf   = (unsigned short*)(ws + OFF_EABF);
  unsigned short* wout_bf = (unsigned short*)(ws + OFF_WOUTBF);
  unsigned short* ipw_bf  = (unsigned short*)(ws + OFF_IPWBF);
  unsigned short* wlin_bf = (unsigned short*)(ws + OFF_WLINBF);
  unsigned short* wedg_bf = (unsigned short*)(ws + OFF_WEDGBF);
  unsigned short* F       = (unsigned short*)(ws + OFF_F);
  unsigned short* G       = (unsigned short*)(ws + OFF_G);
  int*            cnt_e   = (int*)(ws + OFF_CNTE);
  int*            cnt_n   = (int*)(ws + OFF_CNTN);
  int*            noe     = (int*)(ws + OFF_NOE);
  int*            eon     = (int*)(ws + OFF_EON);

  // 1. all converts + counter zeroing
  f2b_all<<<1616, 256, 0, stream>>>(x, ea, ipw, wlin, wedge, wout,
                                    x_bf, ea_bf, ipw_bf, wlin_bf, wedg_bf, wout_bf,
                                    cnt_e);
  // 2. adjacency
  build_adj<<<16384, 256, 0, stream>>>(inc, cnt_e, cnt_n, noe, eon);
  // 3. weight fusion (F and G in one dispatch)
  fuse_w<<<dim3(12, 5), 256, 0, stream>>>(ipw_bf, wlin_bf, wedg_bf, F, G);
  // 4. projections: [q | Kn | Vn] = x @ F^T
  gemm_bt<<<dim3(64, 12), 256, 0, stream>>>(x_bf, F, 4096, 768, 256,
                                            MODE_PROJ, q, Kn, Vn, ipb);
  // 5. Ke = edge_attr @ G^T
  gemm_bt<<<dim3(64, 4), 256, 0, stream>>>(ea_bf, G, 4096, 256, 64,
                                           MODE_PLAIN, nullptr, Ke, nullptr, nullptr);
  // 6. attention
  attn_kernel<<<4096, 512, 0, stream>>>(q, Kn, Vn, Ke, eon, noe, ctx);
  // 7. output projection + bias + relu -> d_out (f32)
  gemm_bt<<<dim3(64, 4), 256, 0, stream>>>(ctx, wout_bf, 4096, 256, 256,
                                           MODE_OUT, (float*)d_out, nullptr, nullptr, outb);
}

// Round 3
// 83.508 us; speedup vs baseline: 1.3641x; 1.0618x over previous
//
#include <hip/hip_runtime.h>
#include <hip/hip_bf16.h>

// Problem constants (fixed by the reference file)
#define NN    4096
#define EE    4096
#define DM    256
#define EDIM  64
#define HH    8
#define DHd   32
#define LL    64

typedef short  s16x8 __attribute__((ext_vector_type(8)));
typedef unsigned short u16x8 __attribute__((ext_vector_type(8)));
typedef float  f32x4 __attribute__((ext_vector_type(4)));

__device__ __forceinline__ float b2f(unsigned short u) {
  return __uint_as_float(((unsigned int)u) << 16);
}
__device__ __forceinline__ unsigned short f2b_bits(float f) {
  unsigned int u = __float_as_uint(f);
  u = (u + 0x7FFFu + ((u >> 16) & 1u)) >> 16;   // RNE
  return (unsigned short)u;
}

// ---------------- D1: fused f32->bf16 converts + counter zeroing ----------------
__global__ __launch_bounds__(256) void f2b_all(
    const float* __restrict__ x, const float* __restrict__ ea,
    const float* __restrict__ ipw, const float* __restrict__ wlin,
    const float* __restrict__ wedge, const float* __restrict__ wout,
    unsigned short* __restrict__ xb, unsigned short* __restrict__ eab,
    unsigned short* __restrict__ ipwb, unsigned short* __restrict__ wlinb,
    unsigned short* __restrict__ wedgeb, unsigned short* __restrict__ woutb,
    int* __restrict__ cnt) {
  int i = blockIdx.x * 256 + threadIdx.x;
  if (i < 8192) cnt[i] = 0;                      // zero cnt_e + cnt_n (contiguous)
  const float* src; unsigned short* dst; int j = i;
  if (j < 262144)       { src = x;     dst = xb; }
  else { j -= 262144;
  if (j < 65536)        { src = ea;    dst = eab; }
  else { j -= 65536;
  if (j < 49152)        { src = ipw;   dst = ipwb; }
  else { j -= 49152;
  if (j < 16384)        { src = wlin;  dst = wlinb; }
  else { j -= 16384;
  if (j < 4096)         { src = wedge; dst = wedgeb; }
  else { j -= 4096;
  if (j >= 16384) return;
                          src = wout;  dst = woutb; }}}}}
  float4 v = ((const float4*)src)[j];
  ushort4 o;
  o.x = f2b_bits(v.x); o.y = f2b_bits(v.y); o.z = f2b_bits(v.z); o.w = f2b_bits(v.w);
  ((ushort4*)dst)[j] = o;
}

// ---------------- shared GEMM tile body: C[i][j] = sum_k A[i][k]*B[j][k] ----------------
#define MODE_PLAIN 0
#define MODE_PROJ  1
#define MODE_OUT   2

__device__ __forceinline__ void gemm_tile(
    const unsigned short* __restrict__ A, const unsigned short* __restrict__ B,
    int i0, int j0, int N, int K, int mode,
    float* __restrict__ out_f, unsigned short* __restrict__ out_b,
    unsigned short* __restrict__ out_b2, const float* __restrict__ bias,
    short* As, short* Bs) {
  const int tid  = threadIdx.x;
  const int wid  = tid >> 6, lane = tid & 63;
  const int wr   = (wid >> 1) * 32, wc = (wid & 1) * 32;
  const int srow = tid >> 2, schunk = (tid & 3) * 8;
  const int fr   = lane & 15, fk = (lane >> 4) * 8;

  f32x4 acc[2][2];
#pragma unroll
  for (int a = 0; a < 2; ++a)
#pragma unroll
    for (int b = 0; b < 2; ++b) acc[a][b] = (f32x4){0.f, 0.f, 0.f, 0.f};

  for (int kk = 0; kk < K; kk += 32) {
    *(s16x8*)&As[srow * 40 + schunk] = *(const s16x8*)&A[(size_t)(i0 + srow) * K + kk + schunk];
    *(s16x8*)&Bs[srow * 40 + schunk] = *(const s16x8*)&B[(size_t)(j0 + srow) * K + kk + schunk];
    __syncthreads();
    s16x8 af0 = *(const s16x8*)&As[(wr + fr) * 40 + fk];
    s16x8 af1 = *(const s16x8*)&As[(wr + 16 + fr) * 40 + fk];
    s16x8 bf0 = *(const s16x8*)&Bs[(wc + fr) * 40 + fk];
    s16x8 bf1 = *(const s16x8*)&Bs[(wc + 16 + fr) * 40 + fk];
    acc[0][0] = __builtin_amdgcn_mfma_f32_16x16x32_bf16(af0, bf0, acc[0][0], 0, 0, 0);
    acc[0][1] = __builtin_amdgcn_mfma_f32_16x16x32_bf16(af0, bf1, acc[0][1], 0, 0, 0);
    acc[1][0] = __builtin_amdgcn_mfma_f32_16x16x32_bf16(af1, bf0, acc[1][0], 0, 0, 0);
    acc[1][1] = __builtin_amdgcn_mfma_f32_16x16x32_bf16(af1, bf1, acc[1][1], 0, 0, 0);
    __syncthreads();
  }

  const int ecol = lane & 15, erow0 = (lane >> 4) * 4;
#pragma unroll
  for (int mi = 0; mi < 2; ++mi)
#pragma unroll
    for (int ni = 0; ni < 2; ++ni) {
#pragma unroll
      for (int v = 0; v < 4; ++v) {
        int i = i0 + wr + mi * 16 + erow0 + v;
        int j = j0 + wc + ni * 16 + ecol;
        float val = acc[mi][ni][v];
        if (mode == MODE_PLAIN) {
          out_b[(size_t)i * N + j] = f2b_bits(val);
        } else if (mode == MODE_PROJ) {
          if (j < 256)      out_f[(size_t)i * 256 + j]          = val + bias[j];
          else if (j < 512) out_b[(size_t)i * 256 + (j - 256)]  = f2b_bits(val);
          else              out_b2[(size_t)i * 256 + (j - 512)] = f2b_bits(val + bias[j]);
        } else {
          float r = val + bias[j];
          out_f[(size_t)i * N + j] = r > 0.f ? r : 0.f;
        }
      }
    }
}

// ---------------- D2: build_adj (blocks 0..16383) + fuse_w (blocks 16384..16435) ----------------
// F = ipw @ wlin^T (768x256): 48 blocks; G = Wk @ wedge^T (256x64): 4 blocks.
__global__ __launch_bounds__(256) void adj_fusew(
    const float* __restrict__ inc,
    int* __restrict__ cnt_e, int* __restrict__ cnt_n,
    int* __restrict__ noe, int* __restrict__ eon,
    const unsigned short* __restrict__ ipw_bf, const unsigned short* __restrict__ wlin_bf,
    const unsigned short* __restrict__ wedg_bf,
    unsigned short* __restrict__ F, unsigned short* __restrict__ G) {
  __shared__ short As[64 * 40] __attribute__((aligned(16)));
  __shared__ short Bs[64 * 40] __attribute__((aligned(16)));
  const int bid = blockIdx.x;
  if (bid < 16384) {
    int t = bid * 256 + threadIdx.x;
    float4 v = ((const float4*)inc)[t];
    int flat = t * 4;
    int e  = flat >> 12;
    int u0 = flat & 4095;
    float vals[4] = {v.x, v.y, v.z, v.w};
#pragma unroll
    for (int j = 0; j < 4; ++j) {
      if (vals[j] != 0.0f) {
        int u  = u0 + j;
        int pe = atomicAdd(&cnt_e[e], 1);
        noe[e * 8 + pe] = u;
        int pn = atomicAdd(&cnt_n[u], 1);
        eon[u * 8 + pn] = e;
      }
    }
    return;
  }
  int fb = bid - 16384;
  if (fb < 48) {
    gemm_tile(ipw_bf, wlin_bf, (fb >> 2) * 64, (fb & 3) * 64, 256, 256,
              MODE_PLAIN, nullptr, F, nullptr, nullptr, As, Bs);
  } else {
    gemm_tile(ipw_bf + 256 * 256, wedg_bf, (fb - 48) * 64, 0, 64, 256,
              MODE_PLAIN, nullptr, G, nullptr, nullptr, As, Bs);
  }
}

// ---------------- D3: proj GEMM (768 blocks) + Ke GEMM (256 blocks) ----------------
__global__ __launch_bounds__(256) void proj_ke(
    const unsigned short* __restrict__ x_bf, const unsigned short* __restrict__ F,
    const unsigned short* __restrict__ ea_bf, const unsigned short* __restrict__ G,
    float* __restrict__ q, unsigned short* __restrict__ Kn, unsigned short* __restrict__ Vn,
    unsigned short* __restrict__ Ke, const float* __restrict__ ipb) {
  __shared__ short As[64 * 40] __attribute__((aligned(16)));
  __shared__ short Bs[64 * 40] __attribute__((aligned(16)));
  const int bid = blockIdx.x;
  if (bid < 768) {
    gemm_tile(x_bf, F, (bid & 63) * 64, (bid >> 6) * 64, 768, 256,
              MODE_PROJ, q, Kn, Vn, ipb, As, Bs);
  } else {
    int r = bid - 768;
    gemm_tile(ea_bf, G, (r & 63) * 64, (r >> 6) * 64, 256, 64,
              MODE_PLAIN, nullptr, Ke, nullptr, nullptr, As, Bs);
  }
}

// ---------------- D5: output projection GEMM ----------------
__global__ __launch_bounds__(256) void gemm_out(
    const unsigned short* __restrict__ ctx, const unsigned short* __restrict__ wout_bf,
    float* __restrict__ out, const float* __restrict__ bias) {
  __shared__ short As[64 * 40] __attribute__((aligned(16)));
  __shared__ short Bs[64 * 40] __attribute__((aligned(16)));
  gemm_tile(ctx, wout_bf, blockIdx.x * 64, blockIdx.y * 64, 256, 256,
            MODE_OUT, out, nullptr, nullptr, bias, As, Bs);
}

// ---------------- D4: node-centric attention, registers-only PV ----------------
// 1 block/node, 8 waves = 8 heads. Thread (h=wave, lane): dchunk=lane>>4, rg=lane&15.
// V-staging ownership == PV ownership -> V never touches LDS.
__global__ __launch_bounds__(512) void attn_kernel(
    const float* __restrict__ q, const unsigned short* __restrict__ Kn,
    const unsigned short* __restrict__ Vn, const unsigned short* __restrict__ Ke,
    const int* __restrict__ eon, const int* __restrict__ noe,
    unsigned short* __restrict__ ctx) {
  const int n = blockIdx.x;
  __shared__ int   e_s[8];
  __shared__ int   u_s[64];
  __shared__ float q_s[256];
  __shared__ float qke_s[64];                         // [h*8+e]
  const int tid = threadIdx.x;
  if (tid < 8) e_s[tid] = eon[n * 8 + tid];
  if (tid >= 256 && tid < 320)                        // vectorized q load: 64 x float4
    ((float4*)q_s)[tid - 256] = ((const float4*)(q + (size_t)n * 256))[tid - 256];
  __syncthreads();
  if (tid < 64) {
    u_s[tid] = noe[e_s[tid >> 3] * 8 + (tid & 7)];
  } else if (tid < 128) {
    // qke[h][e] = q[h slice] . Ke[e][h slice]  (dedups 8x-duplicated Ke loads)
    const int h = (tid - 64) >> 3, e = tid & 7;
    const u16x8* ep = (const u16x8*)(Ke + (size_t)e_s[e] * 256 + h * 32);
    float s = 0.f;
#pragma unroll
    for (int c = 0; c < 4; ++c) {
      u16x8 ev = ep[c];
#pragma unroll
      for (int j = 0; j < 8; ++j) s += q_s[h * 32 + c * 8 + j] * b2f(ev[j]);
    }
    qke_s[(h << 3) | e] = s;
  }
  __syncthreads();

  const int h = tid >> 6, lane = tid & 63;
  const int dchunk = lane >> 4, rg = lane & 15;

  // ---- V gather straight into the registers PV will consume (latency hides under scores) ----
  u16x8 vstage[4];
#pragma unroll
  for (int i = 0; i < 4; ++i)
    vstage[i] = *(const u16x8*)(Vn + (size_t)u_s[rg * 4 + i] * 256 + h * 32 + dchunk * 8);

  // ---- scores: pair l = lane ----
  const int u = u_s[lane];
  const u16x8* kp = (const u16x8*)(Kn + ((size_t)u * 256 + h * 32));
  float s = 0.f;
#pragma unroll
  for (int c = 0; c < 4; ++c) {
    u16x8 kv = kp[c];
#pragma unroll
    for (int j = 0; j < 8; ++j) s += q_s[h * 32 + c * 8 + j] * b2f(kv[j]);
  }
  s = (s + qke_s[(h << 3) | (lane >> 3)]) * 0.17677669529663687f;  // 1/sqrt(32)

  // ---- softmax across the 64 pairs (wave-wide) ----
  float m = s;
#pragma unroll
  for (int off = 32; off >= 1; off >>= 1) m = fmaxf(m, __shfl_xor(m, off));
  float p = __expf(s - m);
  float sum = p;
#pragma unroll
  for (int off = 32; off >= 1; off >>= 1) sum += __shfl_xor(sum, off);
  const float a = p / sum;

  // ---- PV in registers: attn weights via shfl, reduce over rg bits ----
  float acc[8];
#pragma unroll
  for (int j = 0; j < 8; ++j) acc[j] = 0.f;
#pragma unroll
  for (int i = 0; i < 4; ++i) {
    float pi = __shfl(a, rg * 4 + i, 64);
#pragma unroll
    for (int j = 0; j < 8; ++j) acc[j] += pi * b2f(vstage[i][j]);
  }
#pragma unroll
  for (int off = 1; off < 16; off <<= 1)
#pragma unroll
    for (int j = 0; j < 8; ++j) acc[j] += __shfl_xor(acc[j], off, 64);

  if (rg == 0) {
    u16x8 o;
#pragma unroll
    for (int j = 0; j < 8; ++j) o[j] = f2b_bits(acc[j]);
    *(u16x8*)(ctx + (size_t)n * 256 + h * 32 + dchunk * 8) = o;
  }
}

// ---------------- workspace layout (bytes) ----------------
#define OFF_Q      ((size_t)0)
#define OFF_KN     ((size_t)4194304)
#define OFF_VN     ((size_t)6291456)
#define OFF_KE     ((size_t)8388608)
#define OFF_CTX    ((size_t)10485760)
#define OFF_XBF    ((size_t)12582912)
#define OFF_EABF   ((size_t)14680064)
#define OFF_WOUTBF ((size_t)15204352)
#define OFF_IPWBF  ((size_t)15335424)
#define OFF_WLINBF ((size_t)15728640)
#define OFF_WEDGBF ((size_t)15859712)
#define OFF_F      ((size_t)15892480)
#define OFF_G      ((size_t)16285696)
#define OFF_CNTE   ((size_t)16318464)
#define OFF_CNTN   ((size_t)16334848)
#define OFF_NOE    ((size_t)16351232)
#define OFF_EON    ((size_t)16482304)

extern "C" void kernel_launch(void* const* d_in, const int* in_sizes, int n_in,
                              void* d_out, int out_size, void* d_ws, size_t ws_size,
                              hipStream_t stream) {
  const float* x     = (const float*)d_in[0];
  const float* inc   = (const float*)d_in[1];
  const float* ea    = (const float*)d_in[2];
  const float* wlin  = (const float*)d_in[3];
  const float* wedge = (const float*)d_in[4];
  const float* ipw   = (const float*)d_in[5];
  const float* ipb   = (const float*)d_in[6];
  const float* wout  = (const float*)d_in[7];
  const float* outb  = (const float*)d_in[8];

  char* ws = (char*)d_ws;
  float*          q       = (float*)(ws + OFF_Q);
  unsigned short* Kn      = (unsigned short*)(ws + OFF_KN);
  unsigned short* Vn      = (unsigned short*)(ws + OFF_VN);
  unsigned short* Ke      = (unsigned short*)(ws + OFF_KE);
  unsigned short* ctx     = (unsigned short*)(ws + OFF_CTX);
  unsigned short* x_bf    = (unsigned short*)(ws + OFF_XBF);
  unsigned short* ea_bf   = (unsigned short*)(ws + OFF_EABF);
  unsigned short* wout_bf = (unsigned short*)(ws + OFF_WOUTBF);
  unsigned short* ipw_bf  = (unsigned short*)(ws + OFF_IPWBF);
  unsigned short* wlin_bf = (unsigned short*)(ws + OFF_WLINBF);
  unsigned short* wedg_bf = (unsigned short*)(ws + OFF_WEDGBF);
  unsigned short* F       = (unsigned short*)(ws + OFF_F);
  unsigned short* G       = (unsigned short*)(ws + OFF_G);
  int*            cnt_e   = (int*)(ws + OFF_CNTE);
  int*            cnt_n   = (int*)(ws + OFF_CNTN);
  int*            noe     = (int*)(ws + OFF_NOE);
  int*            eon     = (int*)(ws + OFF_EON);

  // D1: all converts + counter zeroing
  f2b_all<<<1616, 256, 0, stream>>>(x, ea, ipw, wlin, wedge, wout,
                                    x_bf, ea_bf, ipw_bf, wlin_bf, wedg_bf, wout_bf,
                                    cnt_e);
  // D2: adjacency + weight-fusion GEMMs (independent, co-dispatched)
  adj_fusew<<<16436, 256, 0, stream>>>(inc, cnt_e, cnt_n, noe, eon,
                                       ipw_bf, wlin_bf, wedg_bf, F, G);
  // D3: projections [q|Kn|Vn] = x@F^T  +  Ke = ea@G^T (co-dispatched)
  proj_ke<<<1024, 256, 0, stream>>>(x_bf, F, ea_bf, G, q, Kn, Vn, Ke, ipb);
  // D4: attention
  attn_kernel<<<4096, 512, 0, stream>>>(q, Kn, Vn, Ke, eon, noe, ctx);
  // D5: output projection + bias + relu -> d_out (f32)
  gemm_out<<<dim3(64, 4), 256, 0, stream>>>(ctx, wout_bf, (float*)d_out, outb);
}